// Round 1
// baseline (7977.498 us; speedup 1.0000x reference)
//
#include <hip/hip_runtime.h>
#include <hip/hip_bf16.h>
#include <math.h>

// ---------------------------------------------------------------------------
// Bayesian LSTM, MI355X persistent-kernel design.
//   Phase 1 (prep_kernel): sample weights w = mu + (softplus(rho)+1e-5)*eps,
//     emit bf16 W' = [w_hh | w_ih] (4096 x 1152), bf16 x, bias sums, and
//     per-tensor KL partial sums (Sum(ln sigma + 0.5 eps^2), Sum(w^2)).
//   Phase 2 (lstm_kernel, cooperative, 256 blocks x 256 thr):
//     4 independent batch-groups (32 batches) x 64 blocks. Each block keeps
//     its 64 W'-rows (16 j's x 4 gates) in LDS for all 384 steps; c-state in
//     registers; h double-buffered in ws; per-group monotonic spin barrier.
// ---------------------------------------------------------------------------

#define T_STEPS 384
#define HID 1024
#define KTOT 1152            // HID + IN
#define KP 1160              // padded LDS row stride (bf16 elems) -> 2-way-free banks

// ws layout (bytes)
#define WS_WG    0ull                  // 4096*1152*2 = 9437184
#define WS_XBF   9437184ull            // 384*128*128*2 = 12582912
#define WS_BSUM  22020096ull           // 4096*4
#define WS_ACC   22036480ull           // 8 doubles
#define WS_CTR   22036544ull           // 4 groups * 64B
#define WS_HBUF  22037056ull           // 4 groups * 2 bufs * 32*1024 * 2B = 524288
#define WS_ZERO_LEN (22561344ull - 22036480ull)

#define OUT_HN 50331648ull
#define OUT_CN 50462720ull
#define OUT_KL 50593792ull

typedef __bf16 bf16_t;
typedef bf16_t bf16x8 __attribute__((ext_vector_type(8)));
typedef float f32x4 __attribute__((ext_vector_type(4)));

__device__ __forceinline__ unsigned short f2bf(float f) {
  unsigned int u = __float_as_uint(f);
  u += 0x7fffu + ((u >> 16) & 1u);          // round-to-nearest-even
  return (unsigned short)(u >> 16);
}
__device__ __forceinline__ bf16x8 ld_bf16x8(const unsigned short* p) {
  union { uint4 u; bf16x8 v; } c;
  c.u = *(const uint4*)p;
  return c.v;
}
__device__ __forceinline__ float sigm(float x) { return 1.f / (1.f + __expf(-x)); }
__device__ __forceinline__ float tanh_fast(float x) {
  float ax = fabsf(x);
  float e = __expf(-2.f * ax);
  float t = (1.f - e) / (1.f + e);
  return copysignf(t, x);
}

// ---------------------------------------------------------------------------
__global__ __launch_bounds__(256) void prep_kernel(
    const float* __restrict__ x,
    const float* __restrict__ wim, const float* __restrict__ wir, const float* __restrict__ wie,
    const float* __restrict__ whm, const float* __restrict__ whr, const float* __restrict__ whe,
    const float* __restrict__ bim, const float* __restrict__ bir, const float* __restrict__ bie,
    const float* __restrict__ bhm, const float* __restrict__ bhr, const float* __restrict__ bhe,
    unsigned short* __restrict__ Wg, unsigned short* __restrict__ xbf,
    float* __restrict__ bsum, double* __restrict__ accd)
{
  const int NHH = 4194304, NIH = 524288, NB = 4096, NX = 6291456;
  const int NTOT = NHH + NIH + NB + NX;
  double a0=0,a1=0,a2=0,a3=0,a4=0,a5=0,a6=0,a7=0;
  int stride = gridDim.x * blockDim.x;
  for (int i = blockIdx.x * blockDim.x + threadIdx.x; i < NTOT; i += stride) {
    if (i < NHH) {                                   // w_hh -> W'[g][0:1024]
      int g = i >> 10, k = i & 1023;
      float sg = log1pf(expf(whr[i])) + 1e-5f;
      float eps = whe[i];
      float w = fmaf(sg, eps, whm[i]);
      Wg[(size_t)g * KTOT + k] = f2bf(w);
      a2 += (double)(logf(sg) + 0.5f * eps * eps);
      a3 += (double)w * (double)w;
    } else if (i < NHH + NIH) {                      // w_ih -> W'[g][1024:1152]
      int j = i - NHH;
      int g = j >> 7, k = j & 127;
      float sg = log1pf(expf(wir[j])) + 1e-5f;
      float eps = wie[j];
      float w = fmaf(sg, eps, wim[j]);
      Wg[(size_t)g * KTOT + HID + k] = f2bf(w);
      a0 += (double)(logf(sg) + 0.5f * eps * eps);
      a1 += (double)w * (double)w;
    } else if (i < NHH + NIH + NB) {                 // biases
      int k = i - NHH - NIH;
      float sg1 = log1pf(expf(bir[k])) + 1e-5f;
      float e1 = bie[k];
      float w1 = fmaf(sg1, e1, bim[k]);
      a4 += (double)(logf(sg1) + 0.5f * e1 * e1);
      a5 += (double)w1 * (double)w1;
      float sg2 = log1pf(expf(bhr[k])) + 1e-5f;
      float e2 = bhe[k];
      float w2 = fmaf(sg2, e2, bhm[k]);
      a6 += (double)(logf(sg2) + 0.5f * e2 * e2);
      a7 += (double)w2 * (double)w2;
      bsum[k] = w1 + w2;
    } else {                                         // x -> bf16
      int k = i - NHH - NIH - NB;
      xbf[k] = f2bf(x[k]);
    }
  }
  double v[8] = {a0,a1,a2,a3,a4,a5,a6,a7};
  int lane = threadIdx.x & 63, wave = threadIdx.x >> 6;
  __shared__ double red[4][8];
  #pragma unroll
  for (int q = 0; q < 8; ++q) {
    double t = v[q];
    #pragma unroll
    for (int o = 32; o > 0; o >>= 1) t += __shfl_down(t, o, 64);
    if (lane == 0) red[wave][q] = t;
  }
  __syncthreads();
  if (threadIdx.x == 0) {
    #pragma unroll
    for (int q = 0; q < 8; ++q) {
      double s = red[0][q] + red[1][q] + red[2][q] + red[3][q];
      atomicAdd(&accd[q], s);
    }
  }
}

// ---------------------------------------------------------------------------
__global__ __launch_bounds__(256, 1) void lstm_kernel(
    const unsigned short* __restrict__ Wg, const unsigned short* __restrict__ xbf,
    const float* __restrict__ bsum, unsigned short* __restrict__ hbuf,
    unsigned int* __restrict__ ctrs, const double* __restrict__ accd,
    float* __restrict__ out)
{
  extern __shared__ char smem[];
  unsigned short* Wl = (unsigned short*)smem;                 // 64 x KP bf16 = 148480 B
  float* gbuf = (float*)(smem + (size_t)64 * KP * 2);         // 32 x 68 f32 = 8704 B
  const int tid = threadIdx.x, gid = blockIdx.x;
  const int group = gid >> 6, idx = gid & 63, j0 = idx * 16;

  if (gid == 0 && tid == 0) {
    // KL finalize (logsumexp over tensor-level sums)
    const double L2PI = 1.8378770664093453;
    const double LN_PI = -0.28768207245178085;    // ln 0.75
    const double LN_1MPI = -1.3862943611198906;   // ln 0.25
    const double INV2S1 = 3.694528049465325;      // 1/(2 sigma1^2) = e^2/2
    const double INV2S2 = 601302.1420823884;      // e^14/2
    double Ns[4] = {524288.0, 4194304.0, 4096.0, 4096.0};
    double kl = 0.0;
    #pragma unroll
    for (int tq = 0; tq < 4; ++tq) {
      double post_acc = accd[2*tq], w2 = accd[2*tq+1];
      double N = Ns[tq];
      double post = -0.5 * N * L2PI - post_acc;                       // log q
      double m1 = -0.5 * N * L2PI + N * 1.0 - w2 * INV2S1 + LN_PI;    // ln s1 = -1
      double m2 = -0.5 * N * L2PI + N * 7.0 - w2 * INV2S2 + LN_1MPI;  // ln s2 = -7
      double mx = fmax(m1, m2), mn = fmin(m1, m2);
      double lse = mx + log1p(exp(mn - mx));
      kl += post - lse;
    }
    out[OUT_KL] = (float)kl;
  }

  // Load this block's 64 W'-rows into LDS. LDS row r: gate p=r>>4, j=j0+(r&15)
  {
    int r = tid >> 2, c4 = tid & 3;
    int grow = ((r >> 4) << 10) + j0 + (r & 15);
    const uint4* src = (const uint4*)(Wg + (size_t)grow * KTOT);
    uint4* dst = (uint4*)(smem + (size_t)r * (KP * 2));
    #pragma unroll
    for (int j = 0; j < 36; ++j) dst[c4 + 4 * j] = src[c4 + 4 * j];
  }

  const int lane = tid & 63, wave = tid >> 6;
  const int lq = lane >> 4, ln = lane & 15;
  const int mt = wave >> 1;                       // M-tile (batch half)
  const int nt0 = (wave & 1) * 2, nt1 = nt0 + 1;  // two N-tiles (gate pairs)
  const int arow = mt * 16 + ln;                  // batch-in-group for A-frag

  const unsigned short* WB0 = Wl + (size_t)(nt0 * 16 + ln) * KP + 8 * lq;
  const unsigned short* WB1 = Wl + (size_t)(nt1 * 16 + ln) * KP + 8 * lq;
  unsigned short* hgrp = hbuf + (size_t)group * 65536;   // 2 bufs x 32x1024
  const unsigned short* xrow = xbf + (size_t)(group * 32 + arow) * 128 + 8 * lq;
  unsigned int* ctr = ctrs + group * 16;

  const int brow = tid >> 4, jj = tid & 15;
  const float bia0 = bsum[j0 + jj];
  const float bia1 = bsum[1024 + j0 + jj];
  const float bia2 = bsum[2048 + j0 + jj];
  const float bia3 = bsum[3072 + j0 + jj];
  float c_st0 = 0.f, c_st1 = 0.f;

  __syncthreads();

  for (int t = 0; t < T_STEPS; ++t) {
    // GEMM: gates[b][g-slice] = [h_{t-1} | x_t] @ W'^T   (bf16 MFMA 16x16x32)
    const unsigned short* hr = hgrp + ((t & 1) ^ 1) * 32768 + (size_t)arow * HID + 8 * lq;
    f32x4 acc0 = {0.f,0.f,0.f,0.f}, acc1 = {0.f,0.f,0.f,0.f};
    #pragma unroll 8
    for (int kk = 0; kk < 32; ++kk) {
      bf16x8 a  = ld_bf16x8(hr + 32 * kk);
      bf16x8 b0 = ld_bf16x8(WB0 + 32 * kk);
      bf16x8 b1 = ld_bf16x8(WB1 + 32 * kk);
      acc0 = __builtin_amdgcn_mfma_f32_16x16x32_bf16(a, b0, acc0, 0, 0, 0);
      acc1 = __builtin_amdgcn_mfma_f32_16x16x32_bf16(a, b1, acc1, 0, 0, 0);
    }
    const unsigned short* xr = xrow + (size_t)t * 16384;
    #pragma unroll
    for (int kk = 0; kk < 4; ++kk) {
      bf16x8 a  = ld_bf16x8(xr + 32 * kk);
      bf16x8 b0 = ld_bf16x8(WB0 + HID + 32 * kk);
      bf16x8 b1 = ld_bf16x8(WB1 + HID + 32 * kk);
      acc0 = __builtin_amdgcn_mfma_f32_16x16x32_bf16(a, b0, acc0, 0, 0, 0);
      acc1 = __builtin_amdgcn_mfma_f32_16x16x32_bf16(a, b1, acc1, 0, 0, 0);
    }
    // C layout: col=lane&15 (gate row), row=(lane>>4)*4+r (batch)
    #pragma unroll
    for (int r = 0; r < 4; ++r) {
      int m = mt * 16 + lq * 4 + r;
      gbuf[m * 68 + nt0 * 16 + ln] = acc0[r];
      gbuf[m * 68 + nt1 * 16 + ln] = acc1[r];
    }
    __syncthreads();

    // Gate nonlinearity: two (b, j) pairs per thread; c-state in registers
    unsigned short* hw = hgrp + (t & 1) * 32768;
    #pragma unroll
    for (int pp = 0; pp < 2; ++pp) {
      int b = brow + pp * 16;
      float gi = gbuf[b * 68 + jj]      + bia0;
      float gf = gbuf[b * 68 + 16 + jj] + bia1;
      float gg = gbuf[b * 68 + 32 + jj] + bia2;
      float go = gbuf[b * 68 + 48 + jj] + bia3;
      float cprev = pp ? c_st1 : c_st0;
      float cn = sigm(gf) * cprev + sigm(gi) * tanh_fast(gg);
      float h  = sigm(go) * tanh_fast(cn);
      if (pp) c_st1 = cn; else c_st0 = cn;
      size_t bg = (size_t)(group * 32 + b);
      out[(size_t)t * 131072 + bg * 1024 + j0 + jj] = h;   // ys
      hw[b * 1024 + j0 + jj] = f2bf(h);                    // recurrent feedback
      if (t == T_STEPS - 1) {
        out[OUT_HN + bg * 1024 + j0 + jj] = h;
        out[OUT_CN + bg * 1024 + j0 + jj] = cn;
      }
    }
    __syncthreads();

    // per-group barrier: monotonic counter, release/acquire at agent scope
    if (tid == 0) {
      __threadfence();
      __hip_atomic_fetch_add(ctr, 1u, __ATOMIC_RELEASE, __HIP_MEMORY_SCOPE_AGENT);
      unsigned int tgt = 64u * (unsigned)(t + 1);
      while (__hip_atomic_load(ctr, __ATOMIC_RELAXED, __HIP_MEMORY_SCOPE_AGENT) < tgt)
        __builtin_amdgcn_s_sleep(1);
      __builtin_amdgcn_fence(__ATOMIC_ACQUIRE, "agent");
    }
    __syncthreads();
  }
}

// ---------------------------------------------------------------------------
extern "C" void kernel_launch(void* const* d_in, const int* in_sizes, int n_in,
                              void* d_out, int out_size, void* d_ws, size_t ws_size,
                              hipStream_t stream) {
  const float* x   = (const float*)d_in[0];
  const float* wim = (const float*)d_in[1];
  const float* wir = (const float*)d_in[2];
  const float* wie = (const float*)d_in[3];
  const float* whm = (const float*)d_in[4];
  const float* whr = (const float*)d_in[5];
  const float* whe = (const float*)d_in[6];
  const float* bim = (const float*)d_in[7];
  const float* bir = (const float*)d_in[8];
  const float* bie = (const float*)d_in[9];
  const float* bhm = (const float*)d_in[10];
  const float* bhr = (const float*)d_in[11];
  const float* bhe = (const float*)d_in[12];
  char* ws = (char*)d_ws;
  unsigned short* Wg   = (unsigned short*)(ws + WS_WG);
  unsigned short* xbf  = (unsigned short*)(ws + WS_XBF);
  float*          bsum = (float*)(ws + WS_BSUM);
  double*         accd = (double*)(ws + WS_ACC);
  unsigned int*   ctrs = (unsigned int*)(ws + WS_CTR);
  unsigned short* hbuf = (unsigned short*)(ws + WS_HBUF);
  float* out = (float*)d_out;

  hipMemsetAsync(ws + WS_ACC, 0, WS_ZERO_LEN, stream);
  prep_kernel<<<dim3(1024), dim3(256), 0, stream>>>(
      x, wim, wir, wie, whm, whr, whe, bim, bir, bie, bhm, bhr, bhe,
      Wg, xbf, bsum, accd);

  const int SMEM = 64 * KP * 2 + 32 * 68 * 4;   // 157184 B
  hipFuncSetAttribute((const void*)lstm_kernel,
                      hipFuncAttributeMaxDynamicSharedMemorySize, SMEM);
  const unsigned short* Wg_c = Wg; const unsigned short* xbf_c = xbf;
  const float* bsum_c = bsum; const double* acc_c = accd;
  void* args[] = {(void*)&Wg_c, (void*)&xbf_c, (void*)&bsum_c,
                  (void*)&hbuf, (void*)&ctrs, (void*)&acc_c, (void*)&out};
  hipError_t e = hipLaunchCooperativeKernel((void*)lstm_kernel, dim3(256), dim3(256),
                                            args, (unsigned)SMEM, stream);
  if (e != hipSuccess) {
    // fallback: 256 blocks / 256 CUs at 1 block/CU are co-resident in practice
    lstm_kernel<<<dim3(256), dim3(256), SMEM, stream>>>(Wg_c, xbf_c, bsum_c,
                                                        hbuf, ctrs, acc_c, out);
  }
}

// Round 2
// 3712.826 us; speedup vs baseline: 2.1486x; 2.1486x over previous
//
#include <hip/hip_runtime.h>
#include <hip/hip_bf16.h>
#include <math.h>

// ---------------------------------------------------------------------------
// Bayesian LSTM, MI355X persistent-kernel design, round 2.
//   prep_kernel: sample weights, bf16 W'=[w_hh|w_ih] (4096x1152), bf16 x,
//     bias sums, KL partial sums.
//   lstm_kernel (cooperative, 256 blocks x 256 thr): 4 groups (32 batches) x
//     64 blocks; W'-rows LDS-resident; c in registers; h double-buffered in ws.
//   R2 change: no standalone release fences (they emitted buffer_wbl2 every
//     step = ~20us/step). h feedback = relaxed agent-scope write-through
//     atomic stores + waitcnt; barrier = relaxed RMW + spin; ONE acquire
//     fence (buffer_inv) per block per step; ys stores + x-part MFMAs of
//     step t+1 issued in the barrier shadow; last arriver skips the spin.
// ---------------------------------------------------------------------------

#define T_STEPS 384
#define HID 1024
#define KTOT 1152            // HID + IN
#define KP 1160              // padded LDS row stride (bf16 elems)

// ws layout (bytes)
#define WS_WG    0ull                  // 4096*1152*2 = 9437184
#define WS_XBF   9437184ull            // 384*128*128*2 = 12582912
#define WS_BSUM  22020096ull           // 4096*4
#define WS_ACC   22036480ull           // 8 doubles
#define WS_CTR   22036544ull           // 4 groups * 64B
#define WS_HBUF  22037056ull           // 4 groups * 2 bufs * 32*1024 * 2B
#define WS_ZERO_LEN (22561344ull - 22036480ull)

#define OUT_HN 50331648ull
#define OUT_CN 50462720ull
#define OUT_KL 50593792ull

typedef __bf16 bf16_t;
typedef bf16_t bf16x8 __attribute__((ext_vector_type(8)));
typedef float f32x4 __attribute__((ext_vector_type(4)));

__device__ __forceinline__ unsigned short f2bf(float f) {
  unsigned int u = __float_as_uint(f);
  u += 0x7fffu + ((u >> 16) & 1u);          // round-to-nearest-even
  return (unsigned short)(u >> 16);
}
__device__ __forceinline__ bf16x8 ld_bf16x8(const unsigned short* p) {
  union { uint4 u; bf16x8 v; } c;
  c.u = *(const uint4*)p;
  return c.v;
}
__device__ __forceinline__ float sigm(float x) { return 1.f / (1.f + __expf(-x)); }
__device__ __forceinline__ float tanh_fast(float x) {
  float ax = fabsf(x);
  float e = __expf(-2.f * ax);
  float t = (1.f - e) / (1.f + e);
  return copysignf(t, x);
}

// ---------------------------------------------------------------------------
__global__ __launch_bounds__(256) void prep_kernel(
    const float* __restrict__ x,
    const float* __restrict__ wim, const float* __restrict__ wir, const float* __restrict__ wie,
    const float* __restrict__ whm, const float* __restrict__ whr, const float* __restrict__ whe,
    const float* __restrict__ bim, const float* __restrict__ bir, const float* __restrict__ bie,
    const float* __restrict__ bhm, const float* __restrict__ bhr, const float* __restrict__ bhe,
    unsigned short* __restrict__ Wg, unsigned short* __restrict__ xbf,
    float* __restrict__ bsum, double* __restrict__ accd)
{
  const int NHH = 4194304, NIH = 524288, NB = 4096, NX = 6291456;
  const int NTOT = NHH + NIH + NB + NX;
  double a0=0,a1=0,a2=0,a3=0,a4=0,a5=0,a6=0,a7=0;
  int stride = gridDim.x * blockDim.x;
  for (int i = blockIdx.x * blockDim.x + threadIdx.x; i < NTOT; i += stride) {
    if (i < NHH) {                                   // w_hh -> W'[g][0:1024]
      int g = i >> 10, k = i & 1023;
      float sg = log1pf(expf(whr[i])) + 1e-5f;
      float eps = whe[i];
      float w = fmaf(sg, eps, whm[i]);
      Wg[(size_t)g * KTOT + k] = f2bf(w);
      a2 += (double)(logf(sg) + 0.5f * eps * eps);
      a3 += (double)w * (double)w;
    } else if (i < NHH + NIH) {                      // w_ih -> W'[g][1024:1152]
      int j = i - NHH;
      int g = j >> 7, k = j & 127;
      float sg = log1pf(expf(wir[j])) + 1e-5f;
      float eps = wie[j];
      float w = fmaf(sg, eps, wim[j]);
      Wg[(size_t)g * KTOT + HID + k] = f2bf(w);
      a0 += (double)(logf(sg) + 0.5f * eps * eps);
      a1 += (double)w * (double)w;
    } else if (i < NHH + NIH + NB) {                 // biases
      int k = i - NHH - NIH;
      float sg1 = log1pf(expf(bir[k])) + 1e-5f;
      float e1 = bie[k];
      float w1 = fmaf(sg1, e1, bim[k]);
      a4 += (double)(logf(sg1) + 0.5f * e1 * e1);
      a5 += (double)w1 * (double)w1;
      float sg2 = log1pf(expf(bhr[k])) + 1e-5f;
      float e2 = bhe[k];
      float w2 = fmaf(sg2, e2, bhm[k]);
      a6 += (double)(logf(sg2) + 0.5f * e2 * e2);
      a7 += (double)w2 * (double)w2;
      bsum[k] = w1 + w2;
    } else {                                         // x -> bf16
      int k = i - NHH - NIH - NB;
      xbf[k] = f2bf(x[k]);
    }
  }
  double v[8] = {a0,a1,a2,a3,a4,a5,a6,a7};
  int lane = threadIdx.x & 63, wave = threadIdx.x >> 6;
  __shared__ double red[4][8];
  #pragma unroll
  for (int q = 0; q < 8; ++q) {
    double t = v[q];
    #pragma unroll
    for (int o = 32; o > 0; o >>= 1) t += __shfl_down(t, o, 64);
    if (lane == 0) red[wave][q] = t;
  }
  __syncthreads();
  if (threadIdx.x == 0) {
    #pragma unroll
    for (int q = 0; q < 8; ++q) {
      double s = red[0][q] + red[1][q] + red[2][q] + red[3][q];
      atomicAdd(&accd[q], s);
    }
  }
}

// ---------------------------------------------------------------------------
__global__ __launch_bounds__(256, 1) void lstm_kernel(
    const unsigned short* __restrict__ Wg, const unsigned short* __restrict__ xbf,
    const float* __restrict__ bsum, unsigned short* __restrict__ hbuf,
    unsigned int* __restrict__ ctrs, const double* __restrict__ accd,
    float* __restrict__ out)
{
  extern __shared__ char smem[];
  unsigned short* Wl = (unsigned short*)smem;                 // 64 x KP bf16 = 148480 B
  float* gbuf = (float*)(smem + (size_t)64 * KP * 2);         // 32 x 68 f32 = 8704 B
  const int tid = threadIdx.x, gid = blockIdx.x;
  const int group = gid >> 6, idx = gid & 63, j0 = idx * 16;

  if (gid == 0 && tid == 0) {
    // KL finalize (logsumexp over tensor-level sums)
    const double L2PI = 1.8378770664093453;
    const double LN_PI = -0.28768207245178085;    // ln 0.75
    const double LN_1MPI = -1.3862943611198906;   // ln 0.25
    const double INV2S1 = 3.694528049465325;      // e^2/2
    const double INV2S2 = 601302.1420823884;      // e^14/2
    double Ns[4] = {524288.0, 4194304.0, 4096.0, 4096.0};
    double kl = 0.0;
    #pragma unroll
    for (int tq = 0; tq < 4; ++tq) {
      double post_acc = accd[2*tq], w2 = accd[2*tq+1];
      double N = Ns[tq];
      double post = -0.5 * N * L2PI - post_acc;
      double m1 = -0.5 * N * L2PI + N * 1.0 - w2 * INV2S1 + LN_PI;
      double m2 = -0.5 * N * L2PI + N * 7.0 - w2 * INV2S2 + LN_1MPI;
      double mx = fmax(m1, m2), mn = fmin(m1, m2);
      double lse = mx + log1p(exp(mn - mx));
      kl += post - lse;
    }
    out[OUT_KL] = (float)kl;
  }

  // Load this block's 64 W'-rows into LDS. LDS row r: gate p=r>>4, j=j0+(r&15)
  {
    int r = tid >> 2, c4 = tid & 3;
    int grow = ((r >> 4) << 10) + j0 + (r & 15);
    const uint4* src = (const uint4*)(Wg + (size_t)grow * KTOT);
    uint4* dst = (uint4*)(smem + (size_t)r * (KP * 2));
    #pragma unroll
    for (int j = 0; j < 36; ++j) dst[c4 + 4 * j] = src[c4 + 4 * j];
  }

  const int lane = tid & 63, wave = tid >> 6;
  const int lq = lane >> 4, ln = lane & 15;
  const int mt = wave >> 1;                       // M-tile (batch half)
  const int nt0 = (wave & 1) * 2, nt1 = nt0 + 1;  // two N-tiles (gate pairs)
  const int arow = mt * 16 + ln;                  // batch-in-group for A-frag

  const unsigned short* WB0 = Wl + (size_t)(nt0 * 16 + ln) * KP + 8 * lq;
  const unsigned short* WB1 = Wl + (size_t)(nt1 * 16 + ln) * KP + 8 * lq;
  unsigned short* hgrp = hbuf + (size_t)group * 65536;   // 2 bufs x 32x1024
  const unsigned short* xrow = xbf + (size_t)(group * 32 + arow) * 128 + 8 * lq;
  unsigned int* ctr = ctrs + group * 16;

  // nonlinearity mapping: thread -> (batch b, 2 consecutive j's)
  const int b = tid >> 3, jj0 = (tid & 7) * 2;
  const float2 bi0 = *(const float2*)&bsum[j0 + jj0];
  const float2 bi1 = *(const float2*)&bsum[1024 + j0 + jj0];
  const float2 bi2 = *(const float2*)&bsum[2048 + j0 + jj0];
  const float2 bi3 = *(const float2*)&bsum[3072 + j0 + jj0];
  float c0 = 0.f, c1 = 0.f;

  __syncthreads();

  // prologue: x-part of step 0 (h_{-1}=0 buffer is pre-zeroed by memset)
  f32x4 acc0 = {0.f,0.f,0.f,0.f}, acc1 = {0.f,0.f,0.f,0.f};
  #pragma unroll
  for (int kk = 0; kk < 4; ++kk) {
    bf16x8 a  = ld_bf16x8(xrow + 32 * kk);
    bf16x8 b0 = ld_bf16x8(WB0 + HID + 32 * kk);
    bf16x8 b1 = ld_bf16x8(WB1 + HID + 32 * kk);
    acc0 = __builtin_amdgcn_mfma_f32_16x16x32_bf16(a, b0, acc0, 0, 0, 0);
    acc1 = __builtin_amdgcn_mfma_f32_16x16x32_bf16(a, b1, acc1, 0, 0, 0);
  }

  for (int t = 0; t < T_STEPS; ++t) {
    // h-part GEMM: gates += h_{t-1} @ W_hh^T  (bf16 MFMA 16x16x32)
    const unsigned short* hr = hgrp + ((t & 1) ^ 1) * 32768 + (size_t)arow * HID + 8 * lq;
    #pragma unroll 8
    for (int kk = 0; kk < 32; ++kk) {
      bf16x8 a  = ld_bf16x8(hr + 32 * kk);
      bf16x8 b0 = ld_bf16x8(WB0 + 32 * kk);
      bf16x8 b1 = ld_bf16x8(WB1 + 32 * kk);
      acc0 = __builtin_amdgcn_mfma_f32_16x16x32_bf16(a, b0, acc0, 0, 0, 0);
      acc1 = __builtin_amdgcn_mfma_f32_16x16x32_bf16(a, b1, acc1, 0, 0, 0);
    }
    // C layout: col=lane&15 (gate row), row=(lane>>4)*4+r (batch)
    #pragma unroll
    for (int r = 0; r < 4; ++r) {
      int m = mt * 16 + lq * 4 + r;
      gbuf[m * 68 + nt0 * 16 + ln] = acc0[r];
      gbuf[m * 68 + nt1 * 16 + ln] = acc1[r];
    }
    __syncthreads();

    // gate nonlinearity: (b, jj0), (b, jj0+1); c-state in registers
    float2 gi = *(const float2*)&gbuf[b * 68 + jj0];
    float2 gf = *(const float2*)&gbuf[b * 68 + 16 + jj0];
    float2 gg = *(const float2*)&gbuf[b * 68 + 32 + jj0];
    float2 go = *(const float2*)&gbuf[b * 68 + 48 + jj0];
    float c0n = sigm(gf.x + bi1.x) * c0 + sigm(gi.x + bi0.x) * tanh_fast(gg.x + bi2.x);
    float c1n = sigm(gf.y + bi1.y) * c1 + sigm(gi.y + bi0.y) * tanh_fast(gg.y + bi2.y);
    float h0 = sigm(go.x + bi3.x) * tanh_fast(c0n);
    float h1 = sigm(go.y + bi3.y) * tanh_fast(c1n);
    c0 = c0n; c1 = c1n;

    // recurrent feedback: relaxed agent-scope write-through store (no wbl2)
    unsigned int* hw32 = (unsigned int*)(hgrp + (t & 1) * 32768);
    unsigned int pk = (unsigned)f2bf(h0) | ((unsigned)f2bf(h1) << 16);
    __hip_atomic_store(&hw32[b * 512 + ((j0 + jj0) >> 1)], pk,
                       __ATOMIC_RELAXED, __HIP_MEMORY_SCOPE_AGENT);
    asm volatile("s_waitcnt vmcnt(0)" ::: "memory");
    __syncthreads();                               // all threads' h stores drained

    unsigned int old = 0;
    const unsigned int tgt = 64u * (unsigned)(t + 1);
    const bool last_t = (t == T_STEPS - 1);
    if (tid == 0 && !last_t)
      old = __hip_atomic_fetch_add(ctr, 1u, __ATOMIC_RELAXED, __HIP_MEMORY_SCOPE_AGENT);

    // ---- barrier shadow: ys / hn / cn stores, then x-part of step t+1 ----
    {
      size_t bg = (size_t)(group * 32 + b);
      float2 hs = {h0, h1};
      *(float2*)&out[(size_t)t * 131072 + bg * 1024 + j0 + jj0] = hs;
      if (last_t) {
        *(float2*)&out[OUT_HN + bg * 1024 + j0 + jj0] = hs;
        float2 cs = {c0n, c1n};
        *(float2*)&out[OUT_CN + bg * 1024 + j0 + jj0] = cs;
      }
    }
    if (!last_t) {
      acc0 = (f32x4){0.f,0.f,0.f,0.f};
      acc1 = (f32x4){0.f,0.f,0.f,0.f};
      const unsigned short* xr = xrow + (size_t)(t + 1) * 16384;
      #pragma unroll
      for (int kk = 0; kk < 4; ++kk) {
        bf16x8 a  = ld_bf16x8(xr + 32 * kk);
        bf16x8 b0 = ld_bf16x8(WB0 + HID + 32 * kk);
        bf16x8 b1 = ld_bf16x8(WB1 + HID + 32 * kk);
        acc0 = __builtin_amdgcn_mfma_f32_16x16x32_bf16(a, b0, acc0, 0, 0, 0);
        acc1 = __builtin_amdgcn_mfma_f32_16x16x32_bf16(a, b1, acc1, 0, 0, 0);
      }

      // group barrier: last arriver skips the spin; one acquire inv per step
      if (tid == 0) {
        if (old != tgt - 1) {
          while (__hip_atomic_load(ctr, __ATOMIC_RELAXED, __HIP_MEMORY_SCOPE_AGENT) < tgt)
            __builtin_amdgcn_s_sleep(2);
        }
        __builtin_amdgcn_fence(__ATOMIC_ACQUIRE, "agent");   // buffer_inv
      }
      __syncthreads();
    }
  }
}

// ---------------------------------------------------------------------------
extern "C" void kernel_launch(void* const* d_in, const int* in_sizes, int n_in,
                              void* d_out, int out_size, void* d_ws, size_t ws_size,
                              hipStream_t stream) {
  const float* x   = (const float*)d_in[0];
  const float* wim = (const float*)d_in[1];
  const float* wir = (const float*)d_in[2];
  const float* wie = (const float*)d_in[3];
  const float* whm = (const float*)d_in[4];
  const float* whr = (const float*)d_in[5];
  const float* whe = (const float*)d_in[6];
  const float* bim = (const float*)d_in[7];
  const float* bir = (const float*)d_in[8];
  const float* bie = (const float*)d_in[9];
  const float* bhm = (const float*)d_in[10];
  const float* bhr = (const float*)d_in[11];
  const float* bhe = (const float*)d_in[12];
  char* ws = (char*)d_ws;
  unsigned short* Wg   = (unsigned short*)(ws + WS_WG);
  unsigned short* xbf  = (unsigned short*)(ws + WS_XBF);
  float*          bsum = (float*)(ws + WS_BSUM);
  double*         accd = (double*)(ws + WS_ACC);
  unsigned int*   ctrs = (unsigned int*)(ws + WS_CTR);
  unsigned short* hbuf = (unsigned short*)(ws + WS_HBUF);
  float* out = (float*)d_out;

  hipMemsetAsync(ws + WS_ACC, 0, WS_ZERO_LEN, stream);
  prep_kernel<<<dim3(1024), dim3(256), 0, stream>>>(
      x, wim, wir, wie, whm, whr, whe, bim, bir, bie, bhm, bhr, bhe,
      Wg, xbf, bsum, accd);

  const int SMEM = 64 * KP * 2 + 32 * 68 * 4;   // 157184 B
  hipFuncSetAttribute((const void*)lstm_kernel,
                      hipFuncAttributeMaxDynamicSharedMemorySize, SMEM);
  const unsigned short* Wg_c = Wg; const unsigned short* xbf_c = xbf;
  const float* bsum_c = bsum; const double* acc_c = accd;
  void* args[] = {(void*)&Wg_c, (void*)&xbf_c, (void*)&bsum_c,
                  (void*)&hbuf, (void*)&ctrs, (void*)&acc_c, (void*)&out};
  hipError_t e = hipLaunchCooperativeKernel((void*)lstm_kernel, dim3(256), dim3(256),
                                            args, (unsigned)SMEM, stream);
  if (e != hipSuccess) {
    // fallback: 256 blocks / 256 CUs at 1 block/CU are co-resident in practice
    lstm_kernel<<<dim3(256), dim3(256), SMEM, stream>>>(Wg_c, xbf_c, bsum_c,
                                                        hbuf, ctrs, acc_c, out);
  }
}